// Round 1
// baseline (203.328 us; speedup 1.0000x reference)
//
#include <hip/hip_runtime.h>
#include <math.h>

#define NN      1024   // vector length
#define NB      8      // batch
#define NLAYERS 55     // sum_{b=0..9} (b+1)
#define NPAIRS  512    // NN/2
#define RPB     8      // rows of X per block
#define TPB     256
#define RSTRIDE 12     // rowsT leading-dim pad: 12 floats = 48B (16B aligned, bank-friendly)

__global__ __launch_bounds__(TPB) void diffsort_fused(
    const float* __restrict__ vecs,   // [NB][NN]
    const int*   __restrict__ idx_a,  // [NLAYERS][NPAIRS]
    const int*   __restrict__ idx_b,  // [NLAYERS][NPAIRS]
    float*       __restrict__ out)    // [NB*NN] x, then [NB*NN*NN] X
{
    __shared__ float xs[NN];
    __shared__ float al_s[NPAIRS];
    __shared__ int   ia_s[NPAIRS];
    __shared__ int   ib_s[NPAIRS];
    __shared__ float rowsT[NN][RSTRIDE];   // rowsT[col][r] = X[batch][row0+r][col]

    const int tid   = threadIdx.x;
    const int batch = blockIdx.x >> 7;     // / (NN/RPB) = /128
    const int tile  = blockIdx.x & 127;
    const int row0  = tile * RPB;

    // ---- init: x and identity rows ----
    for (int c = tid; c < NN; c += TPB) {
        xs[c] = vecs[batch * NN + c];
        const int rr = c - row0;
        #pragma unroll
        for (int r = 0; r < RPB; ++r)
            rowsT[c][r] = (r == rr) ? 1.0f : 0.0f;
    }
    __syncthreads();

    for (int layer = 0; layer < NLAYERS; ++layer) {
        const int base = layer * NPAIRS;

        // ---- phase 1: alpha + x update (pairs are disjoint -> race-free) ----
        #pragma unroll
        for (int i = 0; i < NPAIRS / TPB; ++i) {
            const int p  = tid + i * TPB;
            const int ia = idx_a[base + p];
            const int ib = idx_b[base + p];
            const float a = xs[ia];
            const float b = xs[ib];
            const float d   = b - a;
            const float ad  = fabsf(d) + 1e-10f;
            // (|d|+eps)^(-0.25)
            const float pw  = __expf(-0.25f * __logf(ad));
            const float t   = d * 10.0f * pw;
            const float al  = 1.0f / (1.0f + __expf(-t));
            al_s[p] = al;
            ia_s[p] = ia;
            ib_s[p] = ib;
            const float amb = a - b;
            xs[ia] = fmaf( al, amb, b);   // alpha*a + (1-alpha)*b
            xs[ib] = fmaf(-al, amb, a);   // (1-alpha)*a + alpha*b
        }
        __syncthreads();

        // ---- phase 2: row-tile update, 8 rows vectorized as 2x float4 ----
        #pragma unroll
        for (int i = 0; i < NPAIRS / TPB; ++i) {
            const int p  = tid + i * TPB;
            const int ia = ia_s[p];
            const int ib = ib_s[p];
            const float al = al_s[p];
            float4 a0 = *(const float4*)&rowsT[ia][0];
            float4 a1 = *(const float4*)&rowsT[ia][4];
            float4 b0 = *(const float4*)&rowsT[ib][0];
            float4 b1 = *(const float4*)&rowsT[ib][4];
            float4 mn0, mn1, mx0, mx1;
            {
                float d0;
                d0 = a0.x - b0.x; mn0.x = fmaf(al, d0, b0.x); mx0.x = fmaf(-al, d0, a0.x);
                d0 = a0.y - b0.y; mn0.y = fmaf(al, d0, b0.y); mx0.y = fmaf(-al, d0, a0.y);
                d0 = a0.z - b0.z; mn0.z = fmaf(al, d0, b0.z); mx0.z = fmaf(-al, d0, a0.z);
                d0 = a0.w - b0.w; mn0.w = fmaf(al, d0, b0.w); mx0.w = fmaf(-al, d0, a0.w);
                d0 = a1.x - b1.x; mn1.x = fmaf(al, d0, b1.x); mx1.x = fmaf(-al, d0, a1.x);
                d0 = a1.y - b1.y; mn1.y = fmaf(al, d0, b1.y); mx1.y = fmaf(-al, d0, a1.y);
                d0 = a1.z - b1.z; mn1.z = fmaf(al, d0, b1.z); mx1.z = fmaf(-al, d0, a1.z);
                d0 = a1.w - b1.w; mn1.w = fmaf(al, d0, b1.w); mx1.w = fmaf(-al, d0, a1.w);
            }
            *(float4*)&rowsT[ia][0] = mn0;
            *(float4*)&rowsT[ia][4] = mn1;
            *(float4*)&rowsT[ib][0] = mx0;
            *(float4*)&rowsT[ib][4] = mx1;
        }
        __syncthreads();
    }

    // ---- epilogue: write x (one tile per batch) and X rows ----
    if (tile == 0) {
        for (int c = tid; c < NN; c += TPB)
            out[batch * NN + c] = xs[c];
    }
    float* Xo = out + (size_t)NB * NN + (size_t)batch * NN * NN;
    #pragma unroll
    for (int r = 0; r < RPB; ++r) {
        for (int c4 = tid; c4 < NN / 4; c4 += TPB) {
            const int c = c4 * 4;
            float4 v = make_float4(rowsT[c + 0][r], rowsT[c + 1][r],
                                   rowsT[c + 2][r], rowsT[c + 3][r]);
            *(float4*)&Xo[(size_t)(row0 + r) * NN + c] = v;
        }
    }
}

extern "C" void kernel_launch(void* const* d_in, const int* in_sizes, int n_in,
                              void* d_out, int out_size, void* d_ws, size_t ws_size,
                              hipStream_t stream) {
    const float* vecs  = (const float*)d_in[0];
    const int*   idx_a = (const int*)d_in[1];
    const int*   idx_b = (const int*)d_in[2];
    float*       out   = (float*)d_out;

    const int blocks = NB * (NN / RPB);   // 1024
    diffsort_fused<<<blocks, TPB, 0, stream>>>(vecs, idx_a, idx_b, out);
}

// Round 2
// 153.996 us; speedup vs baseline: 1.3203x; 1.3203x over previous
//
#include <hip/hip_runtime.h>
#include <math.h>

#define NN      1024
#define NB      8
#define NLAYERS 55
#define NPAIRS  512

// ---------------- Kernel 1: evolve x, emit per-column alphas ----------------
// One block per batch. x lives in LDS; 512 pairs / 256 threads = 2 pairs/thread.
// alpha stored per COLUMN (same value at both ends of a pair):
//   al_g[batch][layer][col],  new_c = al*v_c + (1-al)*v_partner  for BOTH ends.
__global__ __launch_bounds__(256) void diffsort_alpha(
    const float* __restrict__ vecs,
    const int*   __restrict__ idx_a,
    const int*   __restrict__ idx_b,
    float*       __restrict__ out,    // x -> out[0 .. NB*NN)
    float*       __restrict__ al_g)   // [NB][NLAYERS][NN]
{
    __shared__ float xs[NN];
    const int tid   = threadIdx.x;
    const int batch = blockIdx.x;

    for (int c = tid; c < NN; c += 256) xs[c] = vecs[batch * NN + c];
    __syncthreads();

    for (int l = 0; l < NLAYERS; ++l) {
        float* al = al_g + (size_t)(batch * NLAYERS + l) * NN;
        #pragma unroll
        for (int i = 0; i < 2; ++i) {
            const int p  = tid + i * 256;
            const int ia = idx_a[l * NPAIRS + p];
            const int ib = idx_b[l * NPAIRS + p];
            const float a = xs[ia];
            const float b = xs[ib];
            const float d  = b - a;
            const float ad = fabsf(d) + 1e-10f;
            const float pw = __expf(-0.25f * __logf(ad));   // (|d|+eps)^-0.25
            const float t  = d * 10.0f * pw;
            const float av = 1.0f / (1.0f + __expf(-t));
            al[ia] = av;
            al[ib] = av;
            const float amb = a - b;
            xs[ia] = fmaf( av, amb, b);   // alpha*a + (1-alpha)*b
            xs[ib] = fmaf(-av, amb, a);   // (1-alpha)*a + alpha*b
        }
        __syncthreads();
    }

    for (int c = tid; c < NN; c += 256) out[batch * NN + c] = xs[c];
}

// ---------------- Kernel 2: propagate X rows entirely in registers ----------
// Wave = 4 rows. Lane owns 16 consecutive columns (c = lane*16 + j).
// Partner of column c is c ^ m:
//   m in {1,2,4,8}    -> register-local (j ^ m)
//   m == 16 (L=1)     -> DPP quad_perm [1,0,3,2]    (pure VALU)
//   m == 32 (L=2)     -> DPP quad_perm [2,3,0,1]    (pure VALU)
//   m in {64,128,256} -> ds_swizzle xor (L=4,8,16), conflict-free
//   m == 512 (L=32)   -> shfl_xor 32 (crosses 32-lane halves)

template<int CTRL>
__device__ __forceinline__ float dpp_xor(float x) {
    int i = __builtin_bit_cast(int, x);
    i = __builtin_amdgcn_update_dpp(i, i, CTRL, 0xF, 0xF, false);
    return __builtin_bit_cast(float, i);
}
template<int OFF>
__device__ __forceinline__ float swz_xor(float x) {
    int i = __builtin_bit_cast(int, x);
    i = __builtin_amdgcn_ds_swizzle(i, OFF);
    return __builtin_bit_cast(float, i);
}
__device__ __forceinline__ float shfl32(float x) {
    return __shfl_xor(x, 32, 64);
}

#define RPW 4   // rows per wave

__global__ __launch_bounds__(256, 2) void diffsort_X(
    const float* __restrict__ al_g,
    float*       __restrict__ out)
{
    const int tid   = threadIdx.x;
    const int lane  = tid & 63;
    const int wave  = tid >> 6;
    const int batch = blockIdx.x >> 6;     // 64 row-groups per batch
    const int rg    = blockIdx.x & 63;
    const int row0  = rg * 16 + wave * RPW;
    const int c0    = lane * 16;

    float v[RPW][16];
    #pragma unroll
    for (int r = 0; r < RPW; ++r)
        #pragma unroll
        for (int j = 0; j < 16; ++j)
            v[r][j] = (c0 + j == row0 + r) ? 1.0f : 0.0f;

    const float* alb = al_g + (size_t)batch * NLAYERS * NN + c0;

    #define UPDATE_INLANE(M)                                            \
        { _Pragma("unroll")                                             \
          for (int r = 0; r < RPW; ++r) {                               \
            float nv[16];                                               \
            _Pragma("unroll")                                           \
            for (int j = 0; j < 16; ++j) {                              \
                const float p = v[r][j ^ (M)];                          \
                nv[j] = fmaf(al[j], v[r][j] - p, p);                    \
            }                                                           \
            _Pragma("unroll")                                           \
            for (int j = 0; j < 16; ++j) v[r][j] = nv[j];               \
          } }

    #define UPDATE_XLANE(SHUF)                                          \
        { _Pragma("unroll")                                             \
          for (int r = 0; r < RPW; ++r) {                               \
            _Pragma("unroll")                                           \
            for (int j = 0; j < 16; ++j) {                              \
                const float p = SHUF(v[r][j]);                          \
                v[r][j] = fmaf(al[j], v[r][j] - p, p);                  \
            }                                                           \
          } }

    int layer = 0;
    for (int blk = 0; blk < 10; ++blk) {
        for (int sub = 0; sub <= blk; ++sub, ++layer) {
            const int m = 1 << (blk - sub);

            float al[16];
            const float4* ap = (const float4*)(alb + (size_t)layer * NN);
            *(float4*)&al[0]  = ap[0];
            *(float4*)&al[4]  = ap[1];
            *(float4*)&al[8]  = ap[2];
            *(float4*)&al[12] = ap[3];

            switch (m) {
                case 1:   UPDATE_INLANE(1);                 break;
                case 2:   UPDATE_INLANE(2);                 break;
                case 4:   UPDATE_INLANE(4);                 break;
                case 8:   UPDATE_INLANE(8);                 break;
                case 16:  UPDATE_XLANE(dpp_xor<0xB1>);      break;
                case 32:  UPDATE_XLANE(dpp_xor<0x4E>);      break;
                case 64:  UPDATE_XLANE(swz_xor<0x101F>);    break;
                case 128: UPDATE_XLANE(swz_xor<0x201F>);    break;
                case 256: UPDATE_XLANE(swz_xor<0x401F>);    break;
                case 512: UPDATE_XLANE(shfl32);             break;
            }
        }
    }

    // epilogue: each lane stores its 16 contiguous columns for 4 rows
    float* Xo = out + (size_t)NB * NN + (size_t)batch * NN * NN;
    #pragma unroll
    for (int r = 0; r < RPW; ++r) {
        float* rowp = Xo + (size_t)(row0 + r) * NN + c0;
        #pragma unroll
        for (int q = 0; q < 4; ++q) {
            float4 s = make_float4(v[r][4*q+0], v[r][4*q+1],
                                   v[r][4*q+2], v[r][4*q+3]);
            *(float4*)&rowp[4*q] = s;
        }
    }
}

extern "C" void kernel_launch(void* const* d_in, const int* in_sizes, int n_in,
                              void* d_out, int out_size, void* d_ws, size_t ws_size,
                              hipStream_t stream) {
    const float* vecs  = (const float*)d_in[0];
    const int*   idx_a = (const int*)d_in[1];
    const int*   idx_b = (const int*)d_in[2];
    float*       out   = (float*)d_out;
    float*       al_g  = (float*)d_ws;    // NB*NLAYERS*NN*4 = 1.8 MB

    diffsort_alpha<<<NB, 256, 0, stream>>>(vecs, idx_a, idx_b, out, al_g);
    diffsort_X<<<NB * 64, 256, 0, stream>>>(al_g, out);
}

// Round 3
// 142.078 us; speedup vs baseline: 1.4311x; 1.0839x over previous
//
#include <hip/hip_runtime.h>
#include <math.h>

#define NN  1024
#define NB  8
#define TPB 256
#define RPW 4    // rows per wave

// ---- swizzle for the per-column alpha LDS buffer (float index) ----
// byte ^= ((byte>>7)&7)<<4  ==> float ^= ((f>>5)&7)<<2 ; keeps 16B granules intact,
// spreads the lane-stride-64B b128 reads over all 8 bank groups (conflict-free).
__device__ __forceinline__ int swzf(int f) { return f ^ (((f >> 5) & 7) << 2); }

template<int CTRL>
__device__ __forceinline__ float dpp_xor(float x) {
    int i = __builtin_bit_cast(int, x);
    i = __builtin_amdgcn_update_dpp(i, i, CTRL, 0xF, 0xF, false);
    return __builtin_bit_cast(float, i);
}
template<int OFF>
__device__ __forceinline__ float swz_xor(float x) {
    int i = __builtin_bit_cast(int, x);
    i = __builtin_amdgcn_ds_swizzle(i, OFF);
    return __builtin_bit_cast(float, i);
}
__device__ __forceinline__ float shfl32(float x) { return __shfl_xor(x, 32, 64); }

// ---- alpha producer for one layer: 512 pairs on 256 threads ----
// s = log2(m) (partner distance), t = blk+1 (direction bit).
// Writes per-column alpha (same value at both pair ends) into albuf (swizzled).
__device__ __forceinline__ void a_phase(float* __restrict__ xs,
                                        float* __restrict__ albuf,
                                        int tid, int s, int t) {
    #pragma unroll
    for (int i = 0; i < 2; ++i) {
        const int p  = tid + i * TPB;
        const int j  = p & ((1 << s) - 1);
        const int g  = p >> s;
        const int ix = (g << (s + 1)) | j;
        int a = ix, b = ix + (1 << s);
        if ((ix >> t) & 1) { const int tmp = a; a = b; b = tmp; }
        const float va = xs[a], vb = xs[b];
        const float d  = vb - va;
        const float ad = fabsf(d) + 1e-10f;
        const float pw = __expf(-0.25f * __logf(ad));   // (|d|+eps)^-0.25
        const float tt = d * 10.0f * pw;
        const float av = 1.0f / (1.0f + __expf(-tt));
        albuf[swzf(a)] = av;
        albuf[swzf(b)] = av;
        const float amb = va - vb;
        xs[a] = fmaf( av, amb, vb);   // alpha*a + (1-alpha)*b
        xs[b] = fmaf(-av, amb, va);   // (1-alpha)*a + alpha*b
    }
}

__global__ __launch_bounds__(TPB, 2) void diffsort_fused2(
    const float* __restrict__ vecs,   // [NB][NN]
    float*       __restrict__ out)    // [NB*NN] x, then [NB][NN][NN] X
{
    __shared__ float xs[NN];
    __shared__ float als[2][NN];      // double-buffered per-column alpha (swizzled)

    const int tid   = threadIdx.x;
    const int lane  = tid & 63;
    const int wave  = tid >> 6;
    const int batch = blockIdx.x >> 6;     // 64 row-groups per batch
    const int rg    = blockIdx.x & 63;
    const int row0  = rg * 16 + wave * RPW;
    const int c0    = lane * 16;

    for (int c = tid; c < NN; c += TPB) xs[c] = vecs[batch * NN + c];

    float v[RPW][16];
    #pragma unroll
    for (int r = 0; r < RPW; ++r)
        #pragma unroll
        for (int j = 0; j < 16; ++j)
            v[r][j] = (c0 + j == row0 + r) ? 1.0f : 0.0f;

    __syncthreads();
    a_phase(xs, als[0], tid, 0, 1);        // A(0): blk=0,sub=0 -> s=0,t=1
    __syncthreads();

    #define UPDATE_INLANE(M)                                            \
        { _Pragma("unroll")                                             \
          for (int r = 0; r < RPW; ++r) {                               \
            float nv[16];                                               \
            _Pragma("unroll")                                           \
            for (int j = 0; j < 16; ++j) {                              \
                const float p = v[r][j ^ (M)];                          \
                nv[j] = fmaf(al[j], v[r][j] - p, p);                    \
            }                                                           \
            _Pragma("unroll")                                           \
            for (int j = 0; j < 16; ++j) v[r][j] = nv[j];               \
          } }

    #define UPDATE_XLANE(SHUF)                                          \
        { _Pragma("unroll")                                             \
          for (int r = 0; r < RPW; ++r) {                               \
            _Pragma("unroll")                                           \
            for (int j = 0; j < 16; ++j) {                              \
                const float p = SHUF(v[r][j]);                          \
                v[r][j] = fmaf(al[j], v[r][j] - p, p);                  \
            }                                                           \
          } }

    int layer = 0;
    for (int blk = 0; blk < 10; ++blk) {
        for (int sub = 0; sub <= blk; ++sub, ++layer) {
            // ---- issue alpha loads for B(layer) first (latency hides under A) ----
            float al[16];
            const float* ab = als[layer & 1];
            #pragma unroll
            for (int q = 0; q < 4; ++q) {
                const int f = swzf(c0 + q * 4);
                *(float4*)&al[q * 4] = *(const float4*)&ab[f];
            }

            // ---- A(layer+1): produce next layer's alphas into the other buffer ----
            if (!(blk == 9 && sub == 9)) {
                const int nblk = (sub < blk) ? blk : blk + 1;
                const int nsub = (sub < blk) ? sub + 1 : 0;
                a_phase(xs, als[(layer + 1) & 1], tid, nblk - nsub, nblk + 1);
            }

            // ---- B(layer): register-resident X-row update ----
            const int m = 1 << (blk - sub);
            switch (m) {
                case 1:   UPDATE_INLANE(1);                 break;
                case 2:   UPDATE_INLANE(2);                 break;
                case 4:   UPDATE_INLANE(4);                 break;
                case 8:   UPDATE_INLANE(8);                 break;
                case 16:  UPDATE_XLANE(dpp_xor<0xB1>);      break;  // lane^1
                case 32:  UPDATE_XLANE(dpp_xor<0x4E>);      break;  // lane^2
                case 64:  UPDATE_XLANE(swz_xor<0x101F>);    break;  // lane^4
                case 128: UPDATE_XLANE(swz_xor<0x201F>);    break;  // lane^8
                case 256: UPDATE_XLANE(swz_xor<0x401F>);    break;  // lane^16
                case 512: UPDATE_XLANE(shfl32);             break;  // lane^32
            }
            __syncthreads();
        }
    }

    // ---- epilogue ----
    if (rg == 0)
        for (int c = tid; c < NN; c += TPB) out[batch * NN + c] = xs[c];

    float* Xo = out + (size_t)NB * NN + (size_t)batch * NN * NN;
    #pragma unroll
    for (int r = 0; r < RPW; ++r) {
        float* rowp = Xo + (size_t)(row0 + r) * NN + c0;
        #pragma unroll
        for (int q = 0; q < 4; ++q) {
            float4 s = make_float4(v[r][4*q+0], v[r][4*q+1],
                                   v[r][4*q+2], v[r][4*q+3]);
            *(float4*)&rowp[4*q] = s;
        }
    }
}

extern "C" void kernel_launch(void* const* d_in, const int* in_sizes, int n_in,
                              void* d_out, int out_size, void* d_ws, size_t ws_size,
                              hipStream_t stream) {
    const float* vecs = (const float*)d_in[0];
    float*       out  = (float*)d_out;
    diffsort_fused2<<<NB * 64, TPB, 0, stream>>>(vecs, out);
}